// Round 5
// baseline (182.123 us; speedup 1.0000x reference)
//
#include <hip/hip_runtime.h>
#include <stdint.h>

// ---------------------------------------------------------------------------
// Model history: NOT BW-bound (46% HBM), NOT miss-traffic-bound (XCD swizzle
// cut 7MB fetch, time flat), NOT per-unique-line request-bound (round-3 coop
// gather merged 4 same-line requests into 1 instruction: time flat). Best fit:
// latency x MSHR bound on UNIQUE MISS LINES (~13 cy/line = ~600cy latency /
// ~45 slots). Current px touches 2 unique lines (rec 64B + fzq 16B).
// This round: 128-B fused per-face record [tc f32 x6 | 18 halfs | pad |
// fzr[4 batches] x float4] -> same 5 dwordx4 loads/px but ONE 128-B line/px.
// Workspace unchanged (F*128 = old rec+fzq). Coop gather reverted (neutral,
// cost occupancy+conflicts). If flat with FETCH down -> structural roofline.
// (Round-4 submission was identical; bench died on GPUAcquisitionTimeout —
// resubmitting unchanged to get the measurement.)
// ---------------------------------------------------------------------------

struct H2 { _Float16 x, y; };
static __device__ __forceinline__ uint32_t packh_u(float a, float b) {
    H2 h; h.x = (_Float16)a; h.y = (_Float16)b;
    return __builtin_bit_cast(uint32_t, h);
}
static __device__ __forceinline__ float packh(float a, float b) {
    return __builtin_bit_cast(float, packh_u(a, b));
}
static __device__ __forceinline__ float asf(uint32_t u) {
    return __builtin_bit_cast(float, u);
}
static __device__ __forceinline__ float2 unph(float w) {
    H2 h = __builtin_bit_cast(H2, w);
    return make_float2((float)h.x, (float)h.y);
}

// rec128 layout (32 floats / 128 B per face, 128-B aligned):
//  w0..w5  : tc f32  (t0.x t0.y t1.x t1.y t2.x t2.y)
//  w6..w8  : (n0.x,n0.y) (n1.x,n1.y) (n2.x,n2.y)   packed halfs
//  w9      : (n0.z,n1.z)
//  w10     : (n2.z,v0.z)
//  w11..w13: (v0.x,v0.y) (v1.x,v1.y) (v2.x,v2.y)
//  w14     : (v1.z,v2.z)
//  w15     : pad
//  w16+4b..w18+4b : fzr (=__fdiv_rn(1,fz)) for batch b; w19+4b pad

// tiny: per-vertex fp16 tables (8 B, aligned)
__global__ __launch_bounds__(256) void prep_tab(
    const float* __restrict__ nrm, const float* __restrict__ vtx,
    uint2* __restrict__ nrmh, uint2* __restrict__ vtxh, int V)
{
    int i = blockIdx.x * 256 + threadIdx.x;
    if (i >= V) return;
    const float* n = nrm + (long)i * 3;
    const float* v = vtx + (long)i * 3;
    nrmh[i] = make_uint2(packh_u(n[0], n[1]), packh_u(n[2], 0.0f));
    vtxh[i] = make_uint2(packh_u(v[0], v[1]), packh_u(v[2], 0.0f));
}

// fused producer: 8-B aligned vertex gathers + LDS-staged fuvz streams for
// all 4 batches + LDS-staged coalesced 128-B record store. B==4 only.
__global__ __launch_bounds__(256) void pack_faces3(
    const float* __restrict__ tc,
    const uint2* __restrict__ nrmh, const uint2* __restrict__ vtxh,
    const int* __restrict__ f_vt, const int* __restrict__ f_vn,
    const int* __restrict__ f_v, const float* __restrict__ fuvz,
    float4* __restrict__ rec, int F, int V)
{
    __shared__ float4 sw[2048];          // 32 KB (fz stage, then record stage)
    float* sf = (float*)sw;
    const int tid  = threadIdx.x;
    const int base = blockIdx.x * 256;
    const int f    = base + tid;
    // full: block-uniform; float4 view of fuvz needs (b*F+base)*9 % 4 == 0,
    // guaranteed when (F*9)%4==0 (base%256==0 -> base*9%4==0).
    const bool full = (base + 256 <= F) && ((((long)F * 9) & 3) == 0);

    float2 t[3]; uint2 N[3], Vv[3];
    if (f < F) {
#pragma unroll
        for (int k = 0; k < 3; ++k) {
            int ivt = f_vt[f * 3 + k];
            ivt = ivt < 0 ? 0 : (ivt >= V ? V - 1 : ivt);
            t[k] = ((const float2*)tc)[ivt];
            int ivn = f_vn[f * 3 + k];
            ivn = ivn < 0 ? 0 : (ivn >= V ? V - 1 : ivn);
            N[k] = nrmh[ivn];
            int iv = f_v[f * 3 + k];
            iv = iv < 0 ? 0 : (iv >= V ? V - 1 : iv);
            Vv[k] = vtxh[iv];
        }
    }

    float fzr[4][3];
    if (full) {
#pragma unroll 1
        for (int b = 0; b < 4; ++b) {
            const float4* src = (const float4*)(fuvz + ((long)b * F + base) * 9);
            __syncthreads();             // sf reuse across iterations
            sw[tid]       = src[tid];
            sw[tid + 256] = src[tid + 256];
            if (tid < 64) sw[tid + 512] = src[tid + 512];
            __syncthreads();
            fzr[b][0] = __fdiv_rn(1.0f, sf[tid * 9 + 2]);
            fzr[b][1] = __fdiv_rn(1.0f, sf[tid * 9 + 5]);
            fzr[b][2] = __fdiv_rn(1.0f, sf[tid * 9 + 8]);
        }
    } else if (f < F) {
#pragma unroll
        for (int b = 0; b < 4; ++b) {
            const float* s = fuvz + ((long)b * F + f) * 9;
            fzr[b][0] = __fdiv_rn(1.0f, s[2]);
            fzr[b][1] = __fdiv_rn(1.0f, s[5]);
            fzr[b][2] = __fdiv_rn(1.0f, s[8]);
        }
    }

    uint32_t w9 = 0, w10 = 0, w14 = 0;
    if (f < F) {
        w9  = (N[0].y  & 0xffffu) | (N[1].y  << 16);
        w10 = (N[2].y  & 0xffffu) | (Vv[0].y << 16);
        w14 = (Vv[1].y & 0xffffu) | (Vv[2].y << 16);
    }
    __syncthreads();                     // done with sf as fz stage

    if (full) {
        float4* o = sw + tid * 8;
        o[0] = make_float4(t[0].x, t[0].y, t[1].x, t[1].y);
        o[1] = make_float4(t[2].x, t[2].y, asf(N[0].x), asf(N[1].x));
        o[2] = make_float4(asf(N[2].x), asf(w9), asf(w10), asf(Vv[0].x));
        o[3] = make_float4(asf(Vv[1].x), asf(Vv[2].x), asf(w14), 0.0f);
#pragma unroll
        for (int b = 0; b < 4; ++b)
            o[4 + b] = make_float4(fzr[b][0], fzr[b][1], fzr[b][2], 0.0f);
        __syncthreads();
        float4* og = rec + (long)base * 8;
#pragma unroll
        for (int j = 0; j < 8; ++j)
            og[tid + 256 * j] = sw[tid + 256 * j];
    } else if (f < F) {
        float4* o = rec + (long)f * 8;   // ragged tail: direct guarded store
        o[0] = make_float4(t[0].x, t[0].y, t[1].x, t[1].y);
        o[1] = make_float4(t[2].x, t[2].y, asf(N[0].x), asf(N[1].x));
        o[2] = make_float4(asf(N[2].x), asf(w9), asf(w10), asf(Vv[0].x));
        o[3] = make_float4(asf(Vv[1].x), asf(Vv[2].x), asf(w14), 0.0f);
#pragma unroll
        for (int b = 0; b < 4; ++b)
            o[4 + b] = make_float4(fzr[b][0], fzr[b][1], fzr[b][2], 0.0f);
    }
}

// Single-line raster: 5 dwordx4 loads/px, all in ONE 128-B record line.
// 1-D grid; swz=1 => batch->XCD affinity. Requires HW % 256 == 0.
__global__ __launch_bounds__(256) void raster_fast5(
    const float4* __restrict__ rec,    // F*8 float4 (128 B/face)
    const float* __restrict__ pose,    // B*16
    const float* __restrict__ depth,   // B*HW
    const int*   __restrict__ fim,     // B*HW
    const float* __restrict__ weight,  // B*HW*3
    float* __restrict__ out,           // B*HW*14
    int F, int HW, int nx, int swz)
{
    __shared__ float sb[256 * 14];
    const int tid = threadIdx.x;
    const int id  = blockIdx.x;
    int b, x;
    if (swz) {
        const int xcd = id & 7;        // MI355X round-robin dispatch
        b = xcd >> 1;
        x = (id >> 3) + ((xcd & 1) ? (nx >> 1) : 0);
    } else {
        b = id / nx;
        x = id - b * nx;
    }
    const int hw  = x * 256 + tid;
    const long p  = (long)b * HW + hw;

    const float* pb = pose + b * 16;
    float R00 = pb[0],  R01 = pb[1],  R02 = pb[2],  t0 = pb[3];
    float R10 = pb[4],  R11 = pb[5],  R12 = pb[6],  t1 = pb[7];
    float R20 = pb[8],  R21 = pb[9],  R22 = pb[10], t2 = pb[11];

    int f = fim[p];
    f = f < 0 ? 0 : (f >= F ? F - 1 : f);
    const float d = depth[p];
    float w0 = weight[p * 3 + 0];
    float w1 = weight[p * 3 + 1];
    float w2 = weight[p * 3 + 2];

    // 5 divergent dwordx4 loads, ONE 128-B line (MSHR-merged to 1 miss/px)
    const float4* R = rec + (long)f * 8;
    float4 a0 = R[0], a1 = R[1], a2 = R[2], a3 = R[3];
    float4 fz = R[4 + b];              // b uniform per block

    // wm[k] = ((1/fz)*w)*d — exact np f32 op order (uv wrap sensitivity);
    // fz.{x,y,z} hold __fdiv_rn(1,fz) (hoisted in pack, bit-identical)
    float wm0 = __fmul_rn(__fmul_rn(fz.x, w0), d);
    float wm1 = __fmul_rn(__fmul_rn(fz.y, w1), d);
    float wm2 = __fmul_rn(__fmul_rn(fz.z, w2), d);

    // uv: bit-exact vs numpy ((a0+a1)+a2), no FMA contraction
    float uv0 = __fadd_rn(__fadd_rn(__fmul_rn(a0.x, wm0), __fmul_rn(a0.z, wm1)),
                          __fmul_rn(a1.x, wm2));
    float uv1 = __fadd_rn(__fadd_rn(__fmul_rn(a0.y, wm0), __fmul_rn(a0.w, wm1)),
                          __fmul_rn(a1.y, wm2));
    uv0 -= floorf(uv0);
    uv1 -= floorf(uv1);

    // unpack per rec layout
    float2 u6  = unph(a1.z);   // n0.xy
    float2 u7  = unph(a1.w);   // n1.xy
    float2 u8  = unph(a2.x);   // n2.xy
    float2 u9  = unph(a2.y);   // (n0.z, n1.z)
    float2 u10 = unph(a2.z);   // (n2.z, v0.z)
    float2 u11 = unph(a2.w);   // v0.xy
    float2 u12 = unph(a3.x);   // v1.xy
    float2 u13 = unph(a3.y);   // v2.xy
    float2 u14 = unph(a3.z);   // (v1.z, v2.z)

    float n0 = u6.x * wm0 + u7.x * wm1 + u8.x * wm2;
    float n1 = u6.y * wm0 + u7.y * wm1 + u8.y * wm2;
    float n2 = u9.x * wm0 + u9.y * wm1 + u10.x * wm2;

    float p0 = u11.x * wm0 + u12.x * wm1 + u13.x * wm2;
    float p1 = u11.y * wm0 + u12.y * wm1 + u13.y * wm2;
    float p2 = u10.y * wm0 + u14.x * wm1 + u14.y * wm2;

    float nn = sqrtf(n0 * n0 + n1 * n1 + n2 * n2);
    float ni = 1.0f / fmaxf(nn, 1e-12f);
    float m0 = n0 * ni, m1 = n1 * ni, m2 = n2 * ni;

    float c0 = R00 * m0 + R01 * m1 + R02 * m2;
    float c1 = R10 * m0 + R11 * m1 + R12 * m2;
    float c2 = R20 * m0 + R21 * m1 + R22 * m2;
    float cn = sqrtf(c0 * c0 + c1 * c1 + c2 * c2);
    float ci = 1.0f / fmaxf(cn, 1e-12f);
    c0 *= ci; c1 *= ci; c2 *= ci;

    float q0 = R00 * p0 + R01 * p1 + R02 * p2 + t0;
    float q1 = R10 * p0 + R11 * p1 + R12 * p2 + t1;
    float q2 = R20 * p0 + R21 * p1 + R22 * p2 + t2;

    // stage 14 channels in LDS, then stream 14336 B coalesced
    float* s = sb + tid * 14;
    s[0]  = uv0; s[1]  = uv1;
    s[2]  = m0;  s[3]  = m1;  s[4]  = m2;
    s[5]  = c0;  s[6]  = c1;  s[7]  = c2;
    s[8]  = p0;  s[9]  = p1;  s[10] = p2;
    s[11] = q0;  s[12] = q1;  s[13] = q2;
    __syncthreads();

    float4* og = (float4*)(out + ((long)b * HW + (long)x * 256) * 14);
    const float4* sv = (const float4*)sb;
#pragma unroll
    for (int j = 0; j < 4; ++j) {
        int k = tid + 256 * j;
        if (k < 896) og[k] = sv[k];
    }
}

// ---- ws_old tier: proven round-2 producers + per-lane raster (rec64+fzq) --
__global__ __launch_bounds__(256) void prep_fz(
    const float* __restrict__ nrm, const float* __restrict__ vtx,
    const float* __restrict__ fuvz,
    uint2* __restrict__ nrmh, uint2* __restrict__ vtxh,
    float4* __restrict__ fzq, int V, long BF)
{
    __shared__ float sf[2304];
    const int tid = threadIdx.x;
    const long base = (long)blockIdx.x * 256;
    const long i = base + tid;

    if (nrmh != nullptr && i < V) {
        const float* n = nrm + i * 3;
        const float* v = vtx + i * 3;
        nrmh[i] = make_uint2(packh_u(n[0], n[1]), packh_u(n[2], 0.0f));
        vtxh[i] = make_uint2(packh_u(v[0], v[1]), packh_u(v[2], 0.0f));
    }

    if (base + 256 <= BF) {
        const float4* src = (const float4*)(fuvz + base * 9);
        float4* d = (float4*)sf;
        d[tid]       = src[tid];
        d[tid + 256] = src[tid + 256];
        if (tid < 64) d[tid + 512] = src[tid + 512];
        __syncthreads();
        fzq[i] = make_float4(__fdiv_rn(1.0f, sf[tid * 9 + 2]),
                             __fdiv_rn(1.0f, sf[tid * 9 + 5]),
                             __fdiv_rn(1.0f, sf[tid * 9 + 8]), 0.0f);
    } else if (i < BF) {
        const float* s = fuvz + i * 9;
        fzq[i] = make_float4(__fdiv_rn(1.0f, s[2]),
                             __fdiv_rn(1.0f, s[5]),
                             __fdiv_rn(1.0f, s[8]), 0.0f);
    }
}

__global__ __launch_bounds__(256) void pack_faces_old(
    const float* __restrict__ tc, const float* __restrict__ nrm,
    const float* __restrict__ vtx,
    const int* __restrict__ f_vt, const int* __restrict__ f_vn,
    const int* __restrict__ f_v,
    float* __restrict__ rec, int F, int V)
{
    int f = blockIdx.x * 256 + threadIdx.x;
    if (f >= F) return;
    float t[6], n[9], v[9];
#pragma unroll
    for (int k = 0; k < 3; ++k) {
        int ivt = f_vt[f * 3 + k];
        ivt = ivt < 0 ? 0 : (ivt >= V ? V - 1 : ivt);
        t[k * 2 + 0] = tc[(long)ivt * 2 + 0];
        t[k * 2 + 1] = tc[(long)ivt * 2 + 1];
        int ivn = f_vn[f * 3 + k];
        ivn = ivn < 0 ? 0 : (ivn >= V ? V - 1 : ivn);
        n[k * 3 + 0] = nrm[(long)ivn * 3 + 0];
        n[k * 3 + 1] = nrm[(long)ivn * 3 + 1];
        n[k * 3 + 2] = nrm[(long)ivn * 3 + 2];
        int iv = f_v[f * 3 + k];
        iv = iv < 0 ? 0 : (iv >= V ? V - 1 : iv);
        v[k * 3 + 0] = vtx[(long)iv * 3 + 0];
        v[k * 3 + 1] = vtx[(long)iv * 3 + 1];
        v[k * 3 + 2] = vtx[(long)iv * 3 + 2];
    }
    float4* o = (float4*)(rec + (long)f * 16);
    o[0] = make_float4(t[0], t[1], t[2], t[3]);
    o[1] = make_float4(t[4], t[5], packh(n[0], n[1]), packh(n[3], n[4]));
    o[2] = make_float4(packh(n[6], n[7]), packh(n[2], n[5]),
                       packh(n[8], v[2]), packh(v[0], v[1]));
    o[3] = make_float4(packh(v[3], v[4]), packh(v[6], v[7]),
                       packh(v[5], v[8]), 0.0f);
}

__global__ __launch_bounds__(256) void raster_fast3(
    const float4* __restrict__ rec, const float4* __restrict__ fzq,
    const float* __restrict__ pose, const float* __restrict__ depth,
    const int*   __restrict__ fim, const float* __restrict__ weight,
    float* __restrict__ out, int F, int HW, int nx, int swz)
{
    __shared__ float sb[256 * 14];
    const int tid = threadIdx.x;
    const int id  = blockIdx.x;
    int b, x;
    if (swz) {
        const int xcd = id & 7;
        b = xcd >> 1;
        x = (id >> 3) + ((xcd & 1) ? (nx >> 1) : 0);
    } else {
        b = id / nx;
        x = id - b * nx;
    }
    const int hw  = x * 256 + tid;
    const long p  = (long)b * HW + hw;
    const float* pb = pose + b * 16;
    float R00 = pb[0],  R01 = pb[1],  R02 = pb[2],  t0 = pb[3];
    float R10 = pb[4],  R11 = pb[5],  R12 = pb[6],  t1 = pb[7];
    float R20 = pb[8],  R21 = pb[9],  R22 = pb[10], t2 = pb[11];
    int f = fim[p];
    f = f < 0 ? 0 : (f >= F ? F - 1 : f);
    const float d = depth[p];
    float w0 = weight[p * 3 + 0];
    float w1 = weight[p * 3 + 1];
    float w2 = weight[p * 3 + 2];
    const float4* R4 = rec + (long)f * 4;
    float4 a0 = R4[0], a1 = R4[1], a2 = R4[2], a3 = R4[3];
    float4 fz = fzq[(long)b * F + f];
    float wm0 = __fmul_rn(__fmul_rn(fz.x, w0), d);
    float wm1 = __fmul_rn(__fmul_rn(fz.y, w1), d);
    float wm2 = __fmul_rn(__fmul_rn(fz.z, w2), d);
    float uv0 = __fadd_rn(__fadd_rn(__fmul_rn(a0.x, wm0), __fmul_rn(a0.z, wm1)),
                          __fmul_rn(a1.x, wm2));
    float uv1 = __fadd_rn(__fadd_rn(__fmul_rn(a0.y, wm0), __fmul_rn(a0.w, wm1)),
                          __fmul_rn(a1.y, wm2));
    uv0 -= floorf(uv0);
    uv1 -= floorf(uv1);
    float2 u6  = unph(a1.z), u7  = unph(a1.w), u8  = unph(a2.x);
    float2 u9  = unph(a2.y), u10 = unph(a2.z), u11 = unph(a2.w);
    float2 u12 = unph(a3.x), u13 = unph(a3.y), u14 = unph(a3.z);
    float n0 = u6.x * wm0 + u7.x * wm1 + u8.x * wm2;
    float n1 = u6.y * wm0 + u7.y * wm1 + u8.y * wm2;
    float n2 = u9.x * wm0 + u9.y * wm1 + u10.x * wm2;
    float p0 = u11.x * wm0 + u12.x * wm1 + u13.x * wm2;
    float p1 = u11.y * wm0 + u12.y * wm1 + u13.y * wm2;
    float p2 = u10.y * wm0 + u14.x * wm1 + u14.y * wm2;
    float nn = sqrtf(n0 * n0 + n1 * n1 + n2 * n2);
    float ni = 1.0f / fmaxf(nn, 1e-12f);
    float m0 = n0 * ni, m1 = n1 * ni, m2 = n2 * ni;
    float c0 = R00 * m0 + R01 * m1 + R02 * m2;
    float c1 = R10 * m0 + R11 * m1 + R12 * m2;
    float c2 = R20 * m0 + R21 * m1 + R22 * m2;
    float cn = sqrtf(c0 * c0 + c1 * c1 + c2 * c2);
    float ci = 1.0f / fmaxf(cn, 1e-12f);
    c0 *= ci; c1 *= ci; c2 *= ci;
    float q0 = R00 * p0 + R01 * p1 + R02 * p2 + t0;
    float q1 = R10 * p0 + R11 * p1 + R12 * p2 + t1;
    float q2 = R20 * p0 + R21 * p1 + R22 * p2 + t2;
    float* s = sb + tid * 14;
    s[0]  = uv0; s[1]  = uv1;
    s[2]  = m0;  s[3]  = m1;  s[4]  = m2;
    s[5]  = c0;  s[6]  = c1;  s[7]  = c2;
    s[8]  = p0;  s[9]  = p1;  s[10] = p2;
    s[11] = q0;  s[12] = q1;  s[13] = q2;
    __syncthreads();
    float4* og = (float4*)(out + ((long)b * HW + (long)x * 256) * 14);
    const float4* sv = (const float4*)sb;
#pragma unroll
    for (int j = 0; j < 4; ++j) {
        int k = tid + 256 * j;
        if (k < 896) og[k] = sv[k];
    }
}

// ---- final fallback: the proven single-kernel path ------------------------
__global__ __launch_bounds__(256) void raster_kernel(
    const float* __restrict__ vertices, const float* __restrict__ texcoords,
    const float* __restrict__ normals,
    const int* __restrict__ f_vt, const int* __restrict__ f_vn,
    const int* __restrict__ f_v,
    const float* __restrict__ pose, const float* __restrict__ depth,
    const int* __restrict__ fim, const float* __restrict__ weight,
    const float* __restrict__ fuvz, float* __restrict__ out, int F, int V,
    int HW)
{
    const int hw = blockIdx.x * 256 + threadIdx.x;
    if (hw >= HW) return;
    const int b  = blockIdx.y;
    const int p  = b * HW + hw;
    const float* pb = pose + b * 16;
    float R00 = pb[0], R01 = pb[1], R02 = pb[2],  t0 = pb[3];
    float R10 = pb[4], R11 = pb[5], R12 = pb[6],  t1 = pb[7];
    float R20 = pb[8], R21 = pb[9], R22 = pb[10], t2 = pb[11];
    int f = fim[p];
    f = f < 0 ? 0 : (f >= F ? F - 1 : f);
    const float d = depth[p];
    const float* fz = fuvz + ((long)b * F + f) * 9;
    float wm[3];
#pragma unroll
    for (int k = 0; k < 3; ++k)
        wm[k] = __fmul_rn(__fmul_rn(__fdiv_rn(1.0f, fz[k * 3 + 2]),
                                    weight[(long)p * 3 + k]), d);
    float u0t[3], u1t[3];
    float n0 = 0.f, n1 = 0.f, n2 = 0.f, p0 = 0.f, p1 = 0.f, p2 = 0.f;
#pragma unroll
    for (int k = 0; k < 3; ++k) {
        int ivt = f_vt[f * 3 + k], ivn = f_vn[f * 3 + k], iv = f_v[f * 3 + k];
        ivt = ivt < 0 ? 0 : (ivt >= V ? V - 1 : ivt);
        ivn = ivn < 0 ? 0 : (ivn >= V ? V - 1 : ivn);
        iv  = iv  < 0 ? 0 : (iv  >= V ? V - 1 : iv);
        const float* tc = texcoords + (long)ivt * 2;
        u0t[k] = __fmul_rn(tc[0], wm[k]);
        u1t[k] = __fmul_rn(tc[1], wm[k]);
        const float* nr = normals + (long)ivn * 3;
        n0 += nr[0] * wm[k]; n1 += nr[1] * wm[k]; n2 += nr[2] * wm[k];
        const float* vv = vertices + (long)iv * 3;
        p0 += vv[0] * wm[k]; p1 += vv[1] * wm[k]; p2 += vv[2] * wm[k];
    }
    float uv0 = __fadd_rn(__fadd_rn(u0t[0], u0t[1]), u0t[2]);
    float uv1 = __fadd_rn(__fadd_rn(u1t[0], u1t[1]), u1t[2]);
    uv0 -= floorf(uv0); uv1 -= floorf(uv1);
    float nn = sqrtf(n0 * n0 + n1 * n1 + n2 * n2);
    float ni = 1.0f / fmaxf(nn, 1e-12f);
    float m0 = n0 * ni, m1 = n1 * ni, m2 = n2 * ni;
    float c0 = R00 * m0 + R01 * m1 + R02 * m2;
    float c1 = R10 * m0 + R11 * m1 + R12 * m2;
    float c2 = R20 * m0 + R21 * m1 + R22 * m2;
    float cn = sqrtf(c0 * c0 + c1 * c1 + c2 * c2);
    float ci = 1.0f / fmaxf(cn, 1e-12f);
    c0 *= ci; c1 *= ci; c2 *= ci;
    float q0 = R00 * p0 + R01 * p1 + R02 * p2 + t0;
    float q1 = R10 * p0 + R11 * p1 + R12 * p2 + t1;
    float q2 = R20 * p0 + R21 * p1 + R22 * p2 + t2;
    float2* o = (float2*)(out + (long)p * 14);
    o[0] = make_float2(uv0, uv1); o[1] = make_float2(m0, m1);
    o[2] = make_float2(m2, c0);   o[3] = make_float2(c1, c2);
    o[4] = make_float2(p0, p1);   o[5] = make_float2(p2, q0);
    o[6] = make_float2(q1, q2);
}

extern "C" void kernel_launch(void* const* d_in, const int* in_sizes, int n_in,
                              void* d_out, int out_size, void* d_ws, size_t ws_size,
                              hipStream_t stream) {
    const float* vertices  = (const float*)d_in[0];
    const float* texcoords = (const float*)d_in[1];
    const float* normals   = (const float*)d_in[2];
    const int*   f_vt      = (const int*)  d_in[3];
    const int*   f_vn      = (const int*)  d_in[4];
    const int*   f_v       = (const int*)  d_in[5];
    const float* pose      = (const float*)d_in[6];
    const float* depth     = (const float*)d_in[7];
    const int*   fim       = (const int*)  d_in[8];
    const float* weight    = (const float*)d_in[9];
    const float* fuvz      = (const float*)d_in[11];   // d_in[10] v_uvz: dead
    float* out = (float*)d_out;

    const int B  = in_sizes[6] / 16;
    const int F  = in_sizes[3] / 3;
    const int V  = in_sizes[1] / 2;
    const int HW = in_sizes[7] / B;
    const long BF = (long)B * F;

    const size_t rec128_bytes = (size_t)F * 128;        // 25.6 MB
    const size_t rec64_bytes  = (size_t)F * 64;
    const size_t fzq_bytes    = (size_t)BF * 16;
    const size_t tab_bytes    = (size_t)V * 8;          // 0.8 MB each
    const bool base_ok = d_ws != nullptr &&
                         (((uintptr_t)d_ws) & 127) == 0 &&  // rec 128B-aligned
                         (HW % 256) == 0;
    const bool ws_new = base_ok && B == 4 &&
                        ws_size >= rec128_bytes + 2 * tab_bytes;
    const bool ws_old = base_ok && ws_size >= rec64_bytes + fzq_bytes;

    const int nx = HW / 256;
    // batch->XCD affinity valid when B==4 and nx even (grid % 8 == 0)
    const int swz = (B == 4 && (nx & 1) == 0) ? 1 : 0;

    if (ws_new) {
        float* rec  = (float*)d_ws;
        uint2* nrmh = (uint2*)((char*)d_ws + rec128_bytes);
        uint2* vtxh = (uint2*)((char*)d_ws + rec128_bytes + tab_bytes);
        prep_tab<<<(V + 255) / 256, 256, 0, stream>>>(
            normals, vertices, nrmh, vtxh, V);
        pack_faces3<<<(F + 255) / 256, 256, 0, stream>>>(
            texcoords, nrmh, vtxh, f_vt, f_vn, f_v, fuvz,
            (float4*)rec, F, V);
        raster_fast5<<<B * nx, 256, 0, stream>>>(
            (const float4*)rec, pose, depth, fim, weight, out, F, HW, nx, swz);
    } else if (ws_old) {
        float* rec = (float*)d_ws;
        float* fzq = (float*)((char*)d_ws + rec64_bytes);
        prep_fz<<<(unsigned)((BF + 255) / 256), 256, 0, stream>>>(
            normals, vertices, fuvz, nullptr, nullptr, (float4*)fzq, V, BF);
        pack_faces_old<<<(F + 255) / 256, 256, 0, stream>>>(
            texcoords, normals, vertices, f_vt, f_vn, f_v, rec, F, V);
        raster_fast3<<<B * nx, 256, 0, stream>>>(
            (const float4*)rec, (const float4*)fzq, pose, depth, fim, weight,
            out, F, HW, nx, swz);
    } else {
        dim3 grid((HW + 255) / 256, B);
        raster_kernel<<<grid, 256, 0, stream>>>(
            vertices, texcoords, normals, f_vt, f_vn, f_v,
            pose, depth, fim, weight, fuvz, out, F, V, HW);
    }
}

// Round 6
// 172.851 us; speedup vs baseline: 1.0536x; 1.0536x over previous
//
#include <hip/hip_runtime.h>
#include <stdint.h>

// ---------------------------------------------------------------------------
// Model history: NOT BW-bound (46% HBM), NOT miss-traffic-bound (swizzle cut
// 7MB fetch, flat), NOT per-instruction-request-bound (coop gather: flat),
// NOT unique-line-count-bound (r5 fused 128B record: lines/px 2->1, FETCH
// 105->69MB, time 44->50us REGRESSION -- the fused 25.6MB table defeated
// per-batch L2 slicing, raising avg miss latency). Surviving model:
// AVG-MISS-LATENCY x limited per-wave MLP. This round: revert to the proven
// fastest rec64+fzq structure (r2, 43.8us, best L2 profile) and process
// 2 px/thread -> 10 divergent dwordx4 in flight per thread before first use
// (2x MLP). Both px staged in 28.7KB LDS, single barrier, 7 float4 st/thread.
// If flat -> TA address-throughput floor (5 mandatory gathers/px) = roofline.
// ---------------------------------------------------------------------------

struct H2 { _Float16 x, y; };
static __device__ __forceinline__ uint32_t packh_u(float a, float b) {
    H2 h; h.x = (_Float16)a; h.y = (_Float16)b;
    return __builtin_bit_cast(uint32_t, h);
}
static __device__ __forceinline__ float packh(float a, float b) {
    return __builtin_bit_cast(float, packh_u(a, b));
}
static __device__ __forceinline__ float asf(uint32_t u) {
    return __builtin_bit_cast(float, u);
}
static __device__ __forceinline__ float2 unph(float w) {
    H2 h = __builtin_bit_cast(H2, w);
    return make_float2((float)h.x, (float)h.y);
}

// rec layout (16 floats / 64 B per face):
//  w0..w5  : tc f32  (t0.x t0.y t1.x t1.y t2.x t2.y)
//  w6..w8  : (n0.x,n0.y) (n1.x,n1.y) (n2.x,n2.y)   packed halfs
//  w9      : (n0.z,n1.z)
//  w10     : (n2.z,v0.z)
//  w11..w13: (v0.x,v0.y) (v1.x,v1.y) (v2.x,v2.y)
//  w14     : (v1.z,v2.z)
//  w15     : pad

// prep: build 8-B fp16 vertex tables + fz reciprocals (LDS-staged reads).
__global__ __launch_bounds__(256) void prep_fz(
    const float* __restrict__ nrm, const float* __restrict__ vtx,
    const float* __restrict__ fuvz,
    uint2* __restrict__ nrmh, uint2* __restrict__ vtxh,
    float4* __restrict__ fzq, int V, long BF)
{
    __shared__ float sf[2304];           // 256 faces * 9 floats
    const int tid = threadIdx.x;
    const long base = (long)blockIdx.x * 256;
    const long i = base + tid;

    if (nrmh != nullptr && i < V) {      // per-vertex fp16 tables (8 B, aligned)
        const float* n = nrm + i * 3;
        const float* v = vtx + i * 3;
        nrmh[i] = make_uint2(packh_u(n[0], n[1]), packh_u(n[2], 0.0f));
        vtxh[i] = make_uint2(packh_u(v[0], v[1]), packh_u(v[2], 0.0f));
    }

    if (base + 256 <= BF) {              // full block: contiguous float4 stage
        const float4* src = (const float4*)(fuvz + base * 9);
        float4* d = (float4*)sf;
        d[tid]       = src[tid];
        d[tid + 256] = src[tid + 256];
        if (tid < 64) d[tid + 512] = src[tid + 512];
        __syncthreads();
        fzq[i] = make_float4(__fdiv_rn(1.0f, sf[tid * 9 + 2]),
                             __fdiv_rn(1.0f, sf[tid * 9 + 5]),
                             __fdiv_rn(1.0f, sf[tid * 9 + 8]), 0.0f);
    } else if (i < BF) {                 // ragged tail (generic shapes)
        const float* s = fuvz + i * 9;
        fzq[i] = make_float4(__fdiv_rn(1.0f, s[2]),
                             __fdiv_rn(1.0f, s[5]),
                             __fdiv_rn(1.0f, s[8]), 0.0f);
    }
}

// pack via 8-B aligned gathers; rec store LDS-staged coalesced.
__global__ __launch_bounds__(256) void pack_faces2(
    const float* __restrict__ tc,
    const uint2* __restrict__ nrmh, const uint2* __restrict__ vtxh,
    const int* __restrict__ f_vt, const int* __restrict__ f_vn,
    const int* __restrict__ f_v,
    float4* __restrict__ rec, int F, int V)
{
    __shared__ float4 sw[1024];          // 256 faces * 64 B
    const int tid  = threadIdx.x;
    const int base = blockIdx.x * 256;
    const int f    = base + tid;

    if (f < F) {
        float2 t[3]; uint2 N[3], Vv[3];
#pragma unroll
        for (int k = 0; k < 3; ++k) {
            int ivt = f_vt[f * 3 + k];
            ivt = ivt < 0 ? 0 : (ivt >= V ? V - 1 : ivt);
            t[k] = ((const float2*)tc)[ivt];
            int ivn = f_vn[f * 3 + k];
            ivn = ivn < 0 ? 0 : (ivn >= V ? V - 1 : ivn);
            N[k] = nrmh[ivn];
            int iv = f_v[f * 3 + k];
            iv = iv < 0 ? 0 : (iv >= V ? V - 1 : iv);
            Vv[k] = vtxh[iv];
        }
        uint32_t w9  = (N[0].y  & 0xffffu) | (N[1].y  << 16);
        uint32_t w10 = (N[2].y  & 0xffffu) | (Vv[0].y << 16);
        uint32_t w14 = (Vv[1].y & 0xffffu) | (Vv[2].y << 16);
        float4* o = sw + tid * 4;
        o[0] = make_float4(t[0].x, t[0].y, t[1].x, t[1].y);
        o[1] = make_float4(t[2].x, t[2].y, asf(N[0].x), asf(N[1].x));
        o[2] = make_float4(asf(N[2].x), asf(w9), asf(w10), asf(Vv[0].x));
        o[3] = make_float4(asf(Vv[1].x), asf(Vv[2].x), asf(w14), 0.0f);
    }
    __syncthreads();
    const int valid  = F - base;
    const int valid4 = (valid < 256 ? valid : 256) * 4;
    float4* og = rec + (long)base * 4;
#pragma unroll
    for (int j = 0; j < 4; ++j) {
        int k = tid + 256 * j;
        if (k < valid4) og[k] = sw[k];
    }
}

// middle-tier fallback producer (f32 gathers, same rec layout, no tables).
__global__ __launch_bounds__(256) void pack_faces_old(
    const float* __restrict__ tc, const float* __restrict__ nrm,
    const float* __restrict__ vtx,
    const int* __restrict__ f_vt, const int* __restrict__ f_vn,
    const int* __restrict__ f_v,
    float* __restrict__ rec, int F, int V)
{
    int f = blockIdx.x * 256 + threadIdx.x;
    if (f >= F) return;
    float t[6], n[9], v[9];
#pragma unroll
    for (int k = 0; k < 3; ++k) {
        int ivt = f_vt[f * 3 + k];
        ivt = ivt < 0 ? 0 : (ivt >= V ? V - 1 : ivt);
        t[k * 2 + 0] = tc[(long)ivt * 2 + 0];
        t[k * 2 + 1] = tc[(long)ivt * 2 + 1];
        int ivn = f_vn[f * 3 + k];
        ivn = ivn < 0 ? 0 : (ivn >= V ? V - 1 : ivn);
        n[k * 3 + 0] = nrm[(long)ivn * 3 + 0];
        n[k * 3 + 1] = nrm[(long)ivn * 3 + 1];
        n[k * 3 + 2] = nrm[(long)ivn * 3 + 2];
        int iv = f_v[f * 3 + k];
        iv = iv < 0 ? 0 : (iv >= V ? V - 1 : iv);
        v[k * 3 + 0] = vtx[(long)iv * 3 + 0];
        v[k * 3 + 1] = vtx[(long)iv * 3 + 1];
        v[k * 3 + 2] = vtx[(long)iv * 3 + 2];
    }
    float4* o = (float4*)(rec + (long)f * 16);
    o[0] = make_float4(t[0], t[1], t[2], t[3]);
    o[1] = make_float4(t[4], t[5], packh(n[0], n[1]), packh(n[3], n[4]));
    o[2] = make_float4(packh(n[6], n[7]), packh(n[2], n[5]),
                       packh(n[8], v[2]), packh(v[0], v[1]));
    o[3] = make_float4(packh(v[3], v[4]), packh(v[6], v[7]),
                       packh(v[5], v[8]), 0.0f);
}

// shared per-pixel shading (identical op order to all proven variants)
static __device__ __forceinline__ void shade_px(
    float4 a0, float4 a1, float4 a2, float4 a3, float4 fz,
    float w0, float w1, float w2, float d,
    float R00, float R01, float R02, float t0,
    float R10, float R11, float R12, float t1,
    float R20, float R21, float R22, float t2,
    float* __restrict__ s)
{
    // wm[k] = ((1/fz)*w)*d — exact np f32 op order (uv wrap sensitivity)
    float wm0 = __fmul_rn(__fmul_rn(fz.x, w0), d);
    float wm1 = __fmul_rn(__fmul_rn(fz.y, w1), d);
    float wm2 = __fmul_rn(__fmul_rn(fz.z, w2), d);

    // uv: bit-exact vs numpy ((a0+a1)+a2), no FMA contraction
    float uv0 = __fadd_rn(__fadd_rn(__fmul_rn(a0.x, wm0), __fmul_rn(a0.z, wm1)),
                          __fmul_rn(a1.x, wm2));
    float uv1 = __fadd_rn(__fadd_rn(__fmul_rn(a0.y, wm0), __fmul_rn(a0.w, wm1)),
                          __fmul_rn(a1.y, wm2));
    uv0 -= floorf(uv0);
    uv1 -= floorf(uv1);

    float2 u6  = unph(a1.z), u7  = unph(a1.w), u8  = unph(a2.x);
    float2 u9  = unph(a2.y), u10 = unph(a2.z), u11 = unph(a2.w);
    float2 u12 = unph(a3.x), u13 = unph(a3.y), u14 = unph(a3.z);

    float n0 = u6.x * wm0 + u7.x * wm1 + u8.x * wm2;
    float n1 = u6.y * wm0 + u7.y * wm1 + u8.y * wm2;
    float n2 = u9.x * wm0 + u9.y * wm1 + u10.x * wm2;

    float p0 = u11.x * wm0 + u12.x * wm1 + u13.x * wm2;
    float p1 = u11.y * wm0 + u12.y * wm1 + u13.y * wm2;
    float p2 = u10.y * wm0 + u14.x * wm1 + u14.y * wm2;

    float nn = sqrtf(n0 * n0 + n1 * n1 + n2 * n2);
    float ni = 1.0f / fmaxf(nn, 1e-12f);
    float m0 = n0 * ni, m1 = n1 * ni, m2 = n2 * ni;

    float c0 = R00 * m0 + R01 * m1 + R02 * m2;
    float c1 = R10 * m0 + R11 * m1 + R12 * m2;
    float c2 = R20 * m0 + R21 * m1 + R22 * m2;
    float cn = sqrtf(c0 * c0 + c1 * c1 + c2 * c2);
    float ci = 1.0f / fmaxf(cn, 1e-12f);
    c0 *= ci; c1 *= ci; c2 *= ci;

    float q0 = R00 * p0 + R01 * p1 + R02 * p2 + t0;
    float q1 = R10 * p0 + R11 * p1 + R12 * p2 + t1;
    float q2 = R20 * p0 + R21 * p1 + R22 * p2 + t2;

    s[0]  = uv0; s[1]  = uv1;
    s[2]  = m0;  s[3]  = m1;  s[4]  = m2;
    s[5]  = c0;  s[6]  = c1;  s[7]  = c2;
    s[8]  = p0;  s[9]  = p1;  s[10] = p2;
    s[11] = q0;  s[12] = q1;  s[13] = q2;
}

// 2 px/thread raster: 10 divergent dwordx4 in flight per thread (2x MLP).
// 1-D grid; swz=1 => batch->XCD affinity. Requires HW % 512 == 0.
__global__ __launch_bounds__(256, 4) void raster_fast6(
    const float4* __restrict__ rec,    // F*4 float4 (64 B/face)
    const float4* __restrict__ fzq,    // B*F float4 (reciprocal fz)
    const float* __restrict__ pose,    // B*16
    const float* __restrict__ depth,   // B*HW
    const int*   __restrict__ fim,     // B*HW
    const float* __restrict__ weight,  // B*HW*3
    float* __restrict__ out,           // B*HW*14
    int F, int HW, int nx, int swz)
{
    __shared__ float sb[512 * 14];     // 28672 B: both px groups staged
    const int tid = threadIdx.x;
    const int id  = blockIdx.x;
    int b, x;
    if (swz) {
        const int xcd = id & 7;        // MI355X round-robin dispatch
        b = xcd >> 1;
        x = (id >> 3) + ((xcd & 1) ? (nx >> 1) : 0);
    } else {
        b = id / nx;
        x = id - b * nx;
    }
    const long pb0 = (long)b * HW + (long)x * 512;   // block's first pixel

    const float* pb = pose + b * 16;
    float R00 = pb[0],  R01 = pb[1],  R02 = pb[2],  t0 = pb[3];
    float R10 = pb[4],  R11 = pb[5],  R12 = pb[6],  t1 = pb[7];
    float R20 = pb[8],  R21 = pb[9],  R22 = pb[10], t2 = pb[11];

    const long p0i = pb0 + tid;
    const long p1i = pb0 + 256 + tid;

    int f0 = fim[p0i];
    f0 = f0 < 0 ? 0 : (f0 >= F ? F - 1 : f0);
    int f1 = fim[p1i];
    f1 = f1 < 0 ? 0 : (f1 >= F ? F - 1 : f1);
    const float d0 = depth[p0i];
    const float d1 = depth[p1i];
    float w00 = weight[p0i * 3 + 0];
    float w01 = weight[p0i * 3 + 1];
    float w02 = weight[p0i * 3 + 2];
    float w10 = weight[p1i * 3 + 0];
    float w11 = weight[p1i * 3 + 1];
    float w12 = weight[p1i * 3 + 2];

    // 10 divergent dwordx4 issued back-to-back: 2 misses overlap per thread
    const float4* Ra = rec + (long)f0 * 4;
    const float4* Rb = rec + (long)f1 * 4;
    float4 A0 = Ra[0], A1 = Ra[1], A2 = Ra[2], A3 = Ra[3];
    float4 B0 = Rb[0], B1 = Rb[1], B2 = Rb[2], B3 = Rb[3];
    float4 fza = fzq[(long)b * F + f0];
    float4 fzb = fzq[(long)b * F + f1];

    shade_px(A0, A1, A2, A3, fza, w00, w01, w02, d0,
             R00, R01, R02, t0, R10, R11, R12, t1, R20, R21, R22, t2,
             sb + tid * 14);
    shade_px(B0, B1, B2, B3, fzb, w10, w11, w12, d1,
             R00, R01, R02, t0, R10, R11, R12, t1, R20, R21, R22, t2,
             sb + (256 + tid) * 14);
    __syncthreads();

    // stream the block's 28672 B coalesced: 7 float4 per thread
    float4* og = (float4*)(out + pb0 * 14);
    const float4* sv = (const float4*)sb;
#pragma unroll
    for (int j = 0; j < 7; ++j)
        og[tid + 256 * j] = sv[tid + 256 * j];
}

// per-lane 1-px raster (proven round-2 path) — ws_old tier / HW%512!=0.
__global__ __launch_bounds__(256) void raster_fast3(
    const float4* __restrict__ rec, const float4* __restrict__ fzq,
    const float* __restrict__ pose, const float* __restrict__ depth,
    const int*   __restrict__ fim, const float* __restrict__ weight,
    float* __restrict__ out, int F, int HW, int nx, int swz)
{
    __shared__ float sb[256 * 14];
    const int tid = threadIdx.x;
    const int id  = blockIdx.x;
    int b, x;
    if (swz) {
        const int xcd = id & 7;
        b = xcd >> 1;
        x = (id >> 3) + ((xcd & 1) ? (nx >> 1) : 0);
    } else {
        b = id / nx;
        x = id - b * nx;
    }
    const long p  = (long)b * HW + (long)x * 256 + tid;
    const float* pb = pose + b * 16;
    float R00 = pb[0],  R01 = pb[1],  R02 = pb[2],  t0 = pb[3];
    float R10 = pb[4],  R11 = pb[5],  R12 = pb[6],  t1 = pb[7];
    float R20 = pb[8],  R21 = pb[9],  R22 = pb[10], t2 = pb[11];
    int f = fim[p];
    f = f < 0 ? 0 : (f >= F ? F - 1 : f);
    const float d = depth[p];
    float w0 = weight[p * 3 + 0];
    float w1 = weight[p * 3 + 1];
    float w2 = weight[p * 3 + 2];
    const float4* R4 = rec + (long)f * 4;
    float4 a0 = R4[0], a1 = R4[1], a2 = R4[2], a3 = R4[3];
    float4 fz = fzq[(long)b * F + f];
    shade_px(a0, a1, a2, a3, fz, w0, w1, w2, d,
             R00, R01, R02, t0, R10, R11, R12, t1, R20, R21, R22, t2,
             sb + tid * 14);
    __syncthreads();
    float4* og = (float4*)(out + ((long)b * HW + (long)x * 256) * 14);
    const float4* sv = (const float4*)sb;
#pragma unroll
    for (int j = 0; j < 4; ++j) {
        int k = tid + 256 * j;
        if (k < 896) og[k] = sv[k];
    }
}

// ---- final fallback: the proven single-kernel path ------------------------
__global__ __launch_bounds__(256) void raster_kernel(
    const float* __restrict__ vertices, const float* __restrict__ texcoords,
    const float* __restrict__ normals,
    const int* __restrict__ f_vt, const int* __restrict__ f_vn,
    const int* __restrict__ f_v,
    const float* __restrict__ pose, const float* __restrict__ depth,
    const int* __restrict__ fim, const float* __restrict__ weight,
    const float* __restrict__ fuvz, float* __restrict__ out, int F, int V,
    int HW)
{
    const int hw = blockIdx.x * 256 + threadIdx.x;
    if (hw >= HW) return;
    const int b  = blockIdx.y;
    const int p  = b * HW + hw;
    const float* pb = pose + b * 16;
    float R00 = pb[0], R01 = pb[1], R02 = pb[2],  t0 = pb[3];
    float R10 = pb[4], R11 = pb[5], R12 = pb[6],  t1 = pb[7];
    float R20 = pb[8], R21 = pb[9], R22 = pb[10], t2 = pb[11];
    int f = fim[p];
    f = f < 0 ? 0 : (f >= F ? F - 1 : f);
    const float d = depth[p];
    const float* fz = fuvz + ((long)b * F + f) * 9;
    float wm[3];
#pragma unroll
    for (int k = 0; k < 3; ++k)
        wm[k] = __fmul_rn(__fmul_rn(__fdiv_rn(1.0f, fz[k * 3 + 2]),
                                    weight[(long)p * 3 + k]), d);
    float u0t[3], u1t[3];
    float n0 = 0.f, n1 = 0.f, n2 = 0.f, p0 = 0.f, p1 = 0.f, p2 = 0.f;
#pragma unroll
    for (int k = 0; k < 3; ++k) {
        int ivt = f_vt[f * 3 + k], ivn = f_vn[f * 3 + k], iv = f_v[f * 3 + k];
        ivt = ivt < 0 ? 0 : (ivt >= V ? V - 1 : ivt);
        ivn = ivn < 0 ? 0 : (ivn >= V ? V - 1 : ivn);
        iv  = iv  < 0 ? 0 : (iv  >= V ? V - 1 : iv);
        const float* tc = texcoords + (long)ivt * 2;
        u0t[k] = __fmul_rn(tc[0], wm[k]);
        u1t[k] = __fmul_rn(tc[1], wm[k]);
        const float* nr = normals + (long)ivn * 3;
        n0 += nr[0] * wm[k]; n1 += nr[1] * wm[k]; n2 += nr[2] * wm[k];
        const float* vv = vertices + (long)iv * 3;
        p0 += vv[0] * wm[k]; p1 += vv[1] * wm[k]; p2 += vv[2] * wm[k];
    }
    float uv0 = __fadd_rn(__fadd_rn(u0t[0], u0t[1]), u0t[2]);
    float uv1 = __fadd_rn(__fadd_rn(u1t[0], u1t[1]), u1t[2]);
    uv0 -= floorf(uv0); uv1 -= floorf(uv1);
    float nn = sqrtf(n0 * n0 + n1 * n1 + n2 * n2);
    float ni = 1.0f / fmaxf(nn, 1e-12f);
    float m0 = n0 * ni, m1 = n1 * ni, m2 = n2 * ni;
    float c0 = R00 * m0 + R01 * m1 + R02 * m2;
    float c1 = R10 * m0 + R11 * m1 + R12 * m2;
    float c2 = R20 * m0 + R21 * m1 + R22 * m2;
    float cn = sqrtf(c0 * c0 + c1 * c1 + c2 * c2);
    float ci = 1.0f / fmaxf(cn, 1e-12f);
    c0 *= ci; c1 *= ci; c2 *= ci;
    float q0 = R00 * p0 + R01 * p1 + R02 * p2 + t0;
    float q1 = R10 * p0 + R11 * p1 + R12 * p2 + t1;
    float q2 = R20 * p0 + R21 * p1 + R22 * p2 + t2;
    float2* o = (float2*)(out + (long)p * 14);
    o[0] = make_float2(uv0, uv1); o[1] = make_float2(m0, m1);
    o[2] = make_float2(m2, c0);   o[3] = make_float2(c1, c2);
    o[4] = make_float2(p0, p1);   o[5] = make_float2(p2, q0);
    o[6] = make_float2(q1, q2);
}

extern "C" void kernel_launch(void* const* d_in, const int* in_sizes, int n_in,
                              void* d_out, int out_size, void* d_ws, size_t ws_size,
                              hipStream_t stream) {
    const float* vertices  = (const float*)d_in[0];
    const float* texcoords = (const float*)d_in[1];
    const float* normals   = (const float*)d_in[2];
    const int*   f_vt      = (const int*)  d_in[3];
    const int*   f_vn      = (const int*)  d_in[4];
    const int*   f_v       = (const int*)  d_in[5];
    const float* pose      = (const float*)d_in[6];
    const float* depth     = (const float*)d_in[7];
    const int*   fim       = (const int*)  d_in[8];
    const float* weight    = (const float*)d_in[9];
    const float* fuvz      = (const float*)d_in[11];   // d_in[10] v_uvz: dead
    float* out = (float*)d_out;

    const int B  = in_sizes[6] / 16;
    const int F  = in_sizes[3] / 3;
    const int V  = in_sizes[1] / 2;
    const int HW = in_sizes[7] / B;
    const long BF = (long)B * F;

    const size_t rec_bytes = (size_t)F * 64;            // 12.8 MB
    const size_t fzq_bytes = (size_t)BF * 16;           // 12.8 MB
    const size_t tab_bytes = (size_t)V * 8;             // 0.8 MB each
    const bool base_ok = d_ws != nullptr &&
                         (((uintptr_t)d_ws) & 127) == 0 &&
                         (HW % 256) == 0;
    const bool ws_new = base_ok &&
                        ws_size >= rec_bytes + fzq_bytes + 2 * tab_bytes;
    const bool ws_old = base_ok && ws_size >= rec_bytes + fzq_bytes;

    if (ws_new) {
        float* rec  = (float*)d_ws;
        float* fzq  = (float*)((char*)d_ws + rec_bytes);
        uint2* nrmh = (uint2*)((char*)d_ws + rec_bytes + fzq_bytes);
        uint2* vtxh = (uint2*)((char*)d_ws + rec_bytes + fzq_bytes + tab_bytes);
        long nb = BF > (long)V ? BF : (long)V;
        prep_fz<<<(unsigned)((nb + 255) / 256), 256, 0, stream>>>(
            normals, vertices, fuvz, nrmh, vtxh, (float4*)fzq, V, BF);
        pack_faces2<<<(F + 255) / 256, 256, 0, stream>>>(
            texcoords, nrmh, vtxh, f_vt, f_vn, f_v, (float4*)rec, F, V);
        if ((HW % 512) == 0) {
            const int nx = HW / 512;
            const int swz = (B == 4 && (nx & 1) == 0) ? 1 : 0;
            raster_fast6<<<B * nx, 256, 0, stream>>>(
                (const float4*)rec, (const float4*)fzq, pose, depth, fim,
                weight, out, F, HW, nx, swz);
        } else {
            const int nx = HW / 256;
            const int swz = (B == 4 && (nx & 1) == 0) ? 1 : 0;
            raster_fast3<<<B * nx, 256, 0, stream>>>(
                (const float4*)rec, (const float4*)fzq, pose, depth, fim,
                weight, out, F, HW, nx, swz);
        }
    } else if (ws_old) {
        float* rec = (float*)d_ws;
        float* fzq = (float*)((char*)d_ws + rec_bytes);
        prep_fz<<<(unsigned)((BF + 255) / 256), 256, 0, stream>>>(
            normals, vertices, fuvz, nullptr, nullptr, (float4*)fzq, V, BF);
        pack_faces_old<<<(F + 255) / 256, 256, 0, stream>>>(
            texcoords, normals, vertices, f_vt, f_vn, f_v, rec, F, V);
        const int nx = HW / 256;
        const int swz = (B == 4 && (nx & 1) == 0) ? 1 : 0;
        raster_fast3<<<B * nx, 256, 0, stream>>>(
            (const float4*)rec, (const float4*)fzq, pose, depth, fim, weight,
            out, F, HW, nx, swz);
    } else {
        dim3 grid((HW + 255) / 256, B);
        raster_kernel<<<grid, 256, 0, stream>>>(
            vertices, texcoords, normals, f_vt, f_vn, f_v,
            pose, depth, fim, weight, fuvz, out, F, V, HW);
    }
}